// Round 7
// baseline (25.829 us; speedup 1.0000x reference)
//
#include <hip/hip_runtime.h>

// ColorReducer: per-pixel argmin_k of d2 = (x2 - 2*cross) + p2, bit-exact vs
// the numpy reference: cross = ((r*pr + g*pg) + b*pb), x2 = ((r*r+g*g)+b*b),
// d2 = (x2 - 2*cross) + p2, first-index tie-break (strict <).
//
// Exactness (verified through R5, absmax 0.0):
//  - contract(off): plain ops == the RN intrinsics R0 used.
//  - pre-doubled pixels: fl(2r*pr)=2*fl(r*pr), fl(2x+2y)=2*fl(x+y) exact
//    -> ((2r*pr+2g*pg)+2b*pb) == 2*cross bitwise.
//  - k=0 seed == +inf seed with strict < (identical winner).
//  - packed v2f ops are per-element IEEE RN == scalar.
// BANNED: nontemporal stores (R1 fail); readfirstlane SGPR arrays (R4 spill).
//
// R6 = R5 (23.6 us) + occupancy fix ONLY:
//  - register diet: pixel regs overwritten in place by pre-doubled values
//    after x2 (live set ~50 VGPR instead of ~70-90).
//  - __launch_bounds__(256, 8): pin 8 waves/SIMD (m69 cliff: VGPR<=64).

typedef float v2f __attribute__((ext_vector_type(2)));

constexpr int HW    = 512 * 512;   // 2^18
constexpr int KCOL  = 16;
constexpr long NPIX = 16L * HW;    // 4,194,304
constexpr int PPT   = 4;

__global__ __launch_bounds__(256, 8) void color_reduce_kernel(
    const float* __restrict__ x,       // (B, 3, H, W)
    const float* __restrict__ pal,     // (16, 3)
    float* __restrict__ out)           // (B, 3, H, W)
{
#pragma clang fp contract(off)
    __shared__ float spal[KCOL * 3];
    if (threadIdx.x < KCOL * 3) spal[threadIdx.x] = pal[threadIdx.x];
    __syncthreads();

    const long t  = (long)blockIdx.x * blockDim.x + threadIdx.x;
    const long n0 = t * PPT;
    const int b   = (int)(n0 >> 18);        // n0 / HW
    const int pix = (int)(n0 & (HW - 1));   // n0 % HW

    const float* base = x + (size_t)b * 3 * HW + pix;
    const float4 rv = *reinterpret_cast<const float4*>(base);
    const float4 gv = *reinterpret_cast<const float4*>(base + HW);
    const float4 bv = *reinterpret_cast<const float4*>(base + 2 * HW);

    v2f rA = {rv.x, rv.y}, rB = {rv.z, rv.w};
    v2f gA = {gv.x, gv.y}, gB = {gv.z, gv.w};
    v2f bA = {bv.x, bv.y}, bB = {bv.z, bv.w};

    // x2 = ((r*r + g*g) + b*b)  [exact reference tree, packed]
    const v2f x2A = ((rA * rA) + (gA * gA)) + (bA * bA);
    const v2f x2B = ((rB * rB) + (gB * gB)) + (bB * bB);

    // Pre-double IN PLACE (exact: fl(r+r)=2r) — original pixels dead after x2.
    rA = rA + rA; gA = gA + gA; bA = bA + bA;
    rB = rB + rB; gB = gB + gB; bB = bB + bB;

    float best0, best1, best2, best3;
    int   k0 = 0, k1 = 0, k2 = 0, k3 = 0;

    {   // k = 0 seeds best (== +inf seed with strict <)
        const float pr = pal[0], pg = pal[1], pb = pal[2];
        const float p2 = ((pr * pr) + (pg * pg)) + (pb * pb);
        const v2f prv = {pr, pr}, pgv = {pg, pg}, pbv = {pb, pb}, p2v = {p2, p2};
        const v2f crA = ((rA * prv) + (gA * pgv)) + (bA * pbv);   // == 2*cross
        const v2f crB = ((rB * prv) + (gB * pgv)) + (bB * pbv);
        const v2f dA  = (x2A - crA) + p2v;                        // exact d2
        const v2f dB  = (x2B - crB) + p2v;
        best0 = dA.x; best1 = dA.y; best2 = dB.x; best3 = dB.y;
    }

#pragma unroll
    for (int k = 1; k < KCOL; ++k) {
        const float pr = pal[3 * k + 0];   // uniform -> s_load/SGPR
        const float pg = pal[3 * k + 1];
        const float pb = pal[3 * k + 2];
        const float p2 = ((pr * pr) + (pg * pg)) + (pb * pb);
        const v2f prv = {pr, pr}, pgv = {pg, pg}, pbv = {pb, pb}, p2v = {p2, p2};
        const v2f crA = ((rA * prv) + (gA * pgv)) + (bA * pbv);
        const v2f crB = ((rB * prv) + (gB * pgv)) + (bB * pbv);
        const v2f dA  = (x2A - crA) + p2v;
        const v2f dB  = (x2B - crB) + p2v;
        if (dA.x < best0) { best0 = dA.x; k0 = k; }   // strict <: np.argmin
        if (dA.y < best1) { best1 = dA.y; k1 = k; }
        if (dB.x < best2) { best2 = dB.x; k2 = k; }
        if (dB.y < best3) { best3 = dB.y; k3 = k; }
    }

    // Gather winning colors from LDS palette (named scalars, no arrays).
    const float o0r = spal[3 * k0 + 0], o0g = spal[3 * k0 + 1], o0b = spal[3 * k0 + 2];
    const float o1r = spal[3 * k1 + 0], o1g = spal[3 * k1 + 1], o1b = spal[3 * k1 + 2];
    const float o2r = spal[3 * k2 + 0], o2g = spal[3 * k2 + 1], o2b = spal[3 * k2 + 2];
    const float o3r = spal[3 * k3 + 0], o3g = spal[3 * k3 + 1], o3b = spal[3 * k3 + 2];

    float* ob = out + (size_t)b * 3 * HW + pix;
    *reinterpret_cast<float4*>(ob)          = make_float4(o0r, o1r, o2r, o3r);
    *reinterpret_cast<float4*>(ob + HW)     = make_float4(o0g, o1g, o2g, o3g);
    *reinterpret_cast<float4*>(ob + 2 * HW) = make_float4(o0b, o1b, o2b, o3b);
}

extern "C" void kernel_launch(void* const* d_in, const int* in_sizes, int n_in,
                              void* d_out, int out_size, void* d_ws, size_t ws_size,
                              hipStream_t stream) {
    const float* x   = (const float*)d_in[0];
    const float* pal = (const float*)d_in[1];
    float* out       = (float*)d_out;

    const int threads = 256;
    const long total_threads = NPIX / PPT;              // 1,048,576
    const int blocks = (int)(total_threads / threads);  // 4096
    color_reduce_kernel<<<blocks, threads, 0, stream>>>(x, pal, out);
}

// Round 8
// 24.985 us; speedup vs baseline: 1.0338x; 1.0338x over previous
//
#include <hip/hip_runtime.h>

// ColorReducer: per-pixel argmin_k of d2 = (x2 - 2*cross) + p2, bit-exact vs
// the numpy reference: cross = ((r*pr + g*pg) + b*pb), x2 = ((r*r+g*g)+b*b),
// d2 = (x2 - 2*cross) + p2, first-index tie-break (strict <).
//
// Exactness (verified R0/R2/R3/R5/R6, absmax 0.0):
//  - contract(off): plain ops == the RN intrinsics R0 used.
//  - pre-doubled pixels: fl(2r*pr)=2*fl(r*pr), fl(2x+2y)=2*fl(x+y) exact
//    -> ((2r*pr+2g*pg)+2b*pb) == 2*cross bitwise.
//  - k=0 seed == +inf seed with strict < (identical winner).
//  - packed v2f ops are per-element IEEE RN == scalar.
// BANNED (measured failures):
//  - nontemporal stores (R1: absmax 0.611)
//  - readfirstlane SGPR palette arrays (R4: spills, 62 us)
//  - __launch_bounds__ min-waves cap (R4/R6: regressed both times)
//
// R7 = R5 math (best, 23.6 us) + finer generation pipeline:
//   PPT 4 -> 2, 8192 blocks -> 4 resident generations (trend R3/R2/R0/R5:
//   0.5 gen 29.4 / 1 gen 27.7 / 2 gen 26.0->23.6; finer = smoother overlap
//   of one generation's stores with the next one's loads).

typedef float v2f __attribute__((ext_vector_type(2)));

constexpr int HW    = 512 * 512;   // 2^18
constexpr int KCOL  = 16;
constexpr long NPIX = 16L * HW;    // 4,194,304
constexpr int PPT   = 2;           // pixels per thread (one float2 per plane)

__global__ __launch_bounds__(256) void color_reduce_kernel(
    const float* __restrict__ x,       // (B, 3, H, W)
    const float* __restrict__ pal,     // (16, 3)
    float* __restrict__ out)           // (B, 3, H, W)
{
#pragma clang fp contract(off)
    __shared__ float spal[KCOL * 3];
    if (threadIdx.x < KCOL * 3) spal[threadIdx.x] = pal[threadIdx.x];
    __syncthreads();

    const long t  = (long)blockIdx.x * blockDim.x + threadIdx.x;
    const long n0 = t * PPT;
    const int b   = (int)(n0 >> 18);        // n0 / HW
    const int pix = (int)(n0 & (HW - 1));   // n0 % HW

    const float* base = x + (size_t)b * 3 * HW + pix;
    const v2f rA = *reinterpret_cast<const v2f*>(base);
    const v2f gA = *reinterpret_cast<const v2f*>(base + HW);
    const v2f bA = *reinterpret_cast<const v2f*>(base + 2 * HW);

    // x2 = ((r*r + g*g) + b*b)  [exact reference tree, packed]
    const v2f x2A = ((rA * rA) + (gA * gA)) + (bA * bA);

    // Pre-doubled pixels (exact: fl(r+r) = 2r).
    const v2f r2A = rA + rA, g2A = gA + gA, b2A = bA + bA;

    float best0, best1;
    int   k0 = 0, k1 = 0;

    {   // k = 0 seeds best (== +inf seed with strict <)
        const float pr = pal[0], pg = pal[1], pb = pal[2];
        const float p2 = ((pr * pr) + (pg * pg)) + (pb * pb);
        const v2f prv = {pr, pr}, pgv = {pg, pg}, pbv = {pb, pb}, p2v = {p2, p2};
        const v2f crA = ((r2A * prv) + (g2A * pgv)) + (b2A * pbv);  // == 2*cross
        const v2f dA  = (x2A - crA) + p2v;                          // exact d2
        best0 = dA.x; best1 = dA.y;
    }

#pragma unroll
    for (int k = 1; k < KCOL; ++k) {
        const float pr = pal[3 * k + 0];   // uniform -> s_load/SGPR
        const float pg = pal[3 * k + 1];
        const float pb = pal[3 * k + 2];
        const float p2 = ((pr * pr) + (pg * pg)) + (pb * pb);
        const v2f prv = {pr, pr}, pgv = {pg, pg}, pbv = {pb, pb}, p2v = {p2, p2};
        const v2f crA = ((r2A * prv) + (g2A * pgv)) + (b2A * pbv);
        const v2f dA  = (x2A - crA) + p2v;
        if (dA.x < best0) { best0 = dA.x; k0 = k; }   // strict <: np.argmin
        if (dA.y < best1) { best1 = dA.y; k1 = k; }
    }

    // Gather winning colors from LDS palette.
    const float o0r = spal[3 * k0 + 0], o0g = spal[3 * k0 + 1], o0b = spal[3 * k0 + 2];
    const float o1r = spal[3 * k1 + 0], o1g = spal[3 * k1 + 1], o1b = spal[3 * k1 + 2];

    float* ob = out + (size_t)b * 3 * HW + pix;
    const v2f oR = {o0r, o1r}, oG = {o0g, o1g}, oB = {o0b, o1b};
    *reinterpret_cast<v2f*>(ob)          = oR;
    *reinterpret_cast<v2f*>(ob + HW)     = oG;
    *reinterpret_cast<v2f*>(ob + 2 * HW) = oB;
}

extern "C" void kernel_launch(void* const* d_in, const int* in_sizes, int n_in,
                              void* d_out, int out_size, void* d_ws, size_t ws_size,
                              hipStream_t stream) {
    const float* x   = (const float*)d_in[0];
    const float* pal = (const float*)d_in[1];
    float* out       = (float*)d_out;

    const int threads = 256;
    const long total_threads = NPIX / PPT;              // 2,097,152
    const int blocks = (int)(total_threads / threads);  // 8192
    color_reduce_kernel<<<blocks, threads, 0, stream>>>(x, pal, out);
}

// Round 9
// 24.187 us; speedup vs baseline: 1.0679x; 1.0330x over previous
//
#include <hip/hip_runtime.h>

// ColorReducer: per-pixel argmin_k of d2 = (x2 - 2*cross) + p2, bit-exact vs
// the numpy reference: cross = ((r*pr + g*pg) + b*pb), x2 = ((r*r+g*g)+b*b),
// d2 = (x2 - 2*cross) + p2, first-index tie-break (strict <).
//
// Exactness (verified R0/R2/R3/R5/R6/R7, absmax 0.0):
//  - contract(off): plain ops == the RN intrinsics R0 used.
//  - pre-doubled pixels: fl(2r*pr)=2*fl(r*pr), fl(2x+2y)=2*fl(x+y) exact
//    -> ((2r*pr+2g*pg)+2b*pb) == 2*cross bitwise.
//  - k=0 seed == +inf seed with strict < (identical winner).
//  - packed v2f ops are per-element IEEE RN == scalar.
// BANNED (measured failures):
//  - nontemporal stores (R1: absmax 0.611)
//  - readfirstlane SGPR palette arrays (R4: spills, 62 us)
//  - __launch_bounds__ min-waves cap (R4/R6: regressed both times)
//  - PPT=2 fine-generations (R7: 25.0) / half-residency pipeline (R3: 29.4)
//
// R8: unconfounded prefetch test. 2048 blocks = EXACTLY full residency
// (8192 waves = 256 CU x 32), 2 iters x PPT=4, ALL SIX plane-loads issued
// up front so iter-1's loads are in flight during iter-0's compute+store
// (compiler emits counted vmcnt: iter-0 compute only waits its own 3).
// Math = R5 verbatim (best, 23.6 us).

typedef float v2f __attribute__((ext_vector_type(2)));

constexpr int HW      = 512 * 512;   // 2^18
constexpr int KCOL    = 16;
constexpr int PPT     = 4;
constexpr int THREADS = 256;
constexpr int BLOCKS  = 2048;                       // full residency exactly
constexpr int SWEEP   = BLOCKS * THREADS * PPT;     // 2,097,152 = 8*HW

// Per-4-pixel packed distance+select, R5 math verbatim.
__device__ __forceinline__ void reduce4(
    const float4 rv, const float4 gv, const float4 bv,
    const float* __restrict__ pal, const float* spal,
    float* __restrict__ ob)
{
#pragma clang fp contract(off)
    const v2f rA = {rv.x, rv.y}, rB = {rv.z, rv.w};
    const v2f gA = {gv.x, gv.y}, gB = {gv.z, gv.w};
    const v2f bA = {bv.x, bv.y}, bB = {bv.z, bv.w};

    const v2f x2A = ((rA * rA) + (gA * gA)) + (bA * bA);
    const v2f x2B = ((rB * rB) + (gB * gB)) + (bB * bB);

    const v2f r2A = rA + rA, g2A = gA + gA, b2A = bA + bA;
    const v2f r2B = rB + rB, g2B = gB + gB, b2B = bB + bB;

    float best0, best1, best2, best3;
    int   k0 = 0, k1 = 0, k2 = 0, k3 = 0;

    {   // k = 0 seeds best (== +inf seed with strict <)
        const float pr = pal[0], pg = pal[1], pb = pal[2];
        const float p2 = ((pr * pr) + (pg * pg)) + (pb * pb);
        const v2f prv = {pr, pr}, pgv = {pg, pg}, pbv = {pb, pb}, p2v = {p2, p2};
        const v2f crA = ((r2A * prv) + (g2A * pgv)) + (b2A * pbv);  // == 2*cross
        const v2f crB = ((r2B * prv) + (g2B * pgv)) + (b2B * pbv);
        const v2f dA  = (x2A - crA) + p2v;
        const v2f dB  = (x2B - crB) + p2v;
        best0 = dA.x; best1 = dA.y; best2 = dB.x; best3 = dB.y;
    }

#pragma unroll
    for (int k = 1; k < KCOL; ++k) {
        const float pr = pal[3 * k + 0];   // uniform -> s_load/SGPR
        const float pg = pal[3 * k + 1];
        const float pb = pal[3 * k + 2];
        const float p2 = ((pr * pr) + (pg * pg)) + (pb * pb);
        const v2f prv = {pr, pr}, pgv = {pg, pg}, pbv = {pb, pb}, p2v = {p2, p2};
        const v2f crA = ((r2A * prv) + (g2A * pgv)) + (b2A * pbv);
        const v2f crB = ((r2B * prv) + (g2B * pgv)) + (b2B * pbv);
        const v2f dA  = (x2A - crA) + p2v;
        const v2f dB  = (x2B - crB) + p2v;
        if (dA.x < best0) { best0 = dA.x; k0 = k; }   // strict <: np.argmin
        if (dA.y < best1) { best1 = dA.y; k1 = k; }
        if (dB.x < best2) { best2 = dB.x; k2 = k; }
        if (dB.y < best3) { best3 = dB.y; k3 = k; }
    }

    const float o0r = spal[3 * k0 + 0], o0g = spal[3 * k0 + 1], o0b = spal[3 * k0 + 2];
    const float o1r = spal[3 * k1 + 0], o1g = spal[3 * k1 + 1], o1b = spal[3 * k1 + 2];
    const float o2r = spal[3 * k2 + 0], o2g = spal[3 * k2 + 1], o2b = spal[3 * k2 + 2];
    const float o3r = spal[3 * k3 + 0], o3g = spal[3 * k3 + 1], o3b = spal[3 * k3 + 2];

    *reinterpret_cast<float4*>(ob)          = make_float4(o0r, o1r, o2r, o3r);
    *reinterpret_cast<float4*>(ob + HW)     = make_float4(o0g, o1g, o2g, o3g);
    *reinterpret_cast<float4*>(ob + 2 * HW) = make_float4(o0b, o1b, o2b, o3b);
}

__global__ __launch_bounds__(THREADS) void color_reduce_kernel(
    const float* __restrict__ x,       // (B, 3, H, W)
    const float* __restrict__ pal,     // (16, 3)
    float* __restrict__ out)           // (B, 3, H, W)
{
    __shared__ float spal[KCOL * 3];
    if (threadIdx.x < KCOL * 3) spal[threadIdx.x] = pal[threadIdx.x];
    __syncthreads();

    const int t4  = (blockIdx.x * THREADS + threadIdx.x) * PPT;  // < 2,097,152
    const int b0  = t4 >> 18;              // in [0, 8)
    const int pix = t4 & (HW - 1);

    const float* base0 = x + (size_t)b0 * 3 * HW + pix;
    const float* base1 = base0 + (size_t)8 * 3 * HW;   // iter 1: b0 + 8, same pix

    // ALL SIX loads issued up front: iter-1's fly under iter-0's compute.
    const float4 rv0 = *reinterpret_cast<const float4*>(base0);
    const float4 gv0 = *reinterpret_cast<const float4*>(base0 + HW);
    const float4 bv0 = *reinterpret_cast<const float4*>(base0 + 2 * HW);
    const float4 rv1 = *reinterpret_cast<const float4*>(base1);
    const float4 gv1 = *reinterpret_cast<const float4*>(base1 + HW);
    const float4 bv1 = *reinterpret_cast<const float4*>(base1 + 2 * HW);

    float* ob0 = out + (size_t)b0 * 3 * HW + pix;
    float* ob1 = ob0 + (size_t)8 * 3 * HW;

    reduce4(rv0, gv0, bv0, pal, spal, ob0);   // waits only its own 3 loads
    reduce4(rv1, gv1, bv1, pal, spal, ob1);
}

extern "C" void kernel_launch(void* const* d_in, const int* in_sizes, int n_in,
                              void* d_out, int out_size, void* d_ws, size_t ws_size,
                              hipStream_t stream) {
    const float* x   = (const float*)d_in[0];
    const float* pal = (const float*)d_in[1];
    float* out       = (float*)d_out;

    color_reduce_kernel<<<BLOCKS, THREADS, 0, stream>>>(x, pal, out);
}